// Round 2
// baseline (643.490 us; speedup 1.0000x reference)
//
#include <hip/hip_runtime.h>
#include <cstdint>
#include <cstddef>

#define S_TOK 8192
#define MDIM  2048
#define NE    64
#define CAP   128
#define NSEG  256   // 32-token segments

typedef float f32x4 __attribute__((ext_vector_type(4)));

// d_out float layout: [0]=l_aux | [1..+67108864)=combine | [..+67108864)=dispatch | [..+64)=exp_counts
static const size_t COMBINE_OFF  = 1;
static const size_t DISPATCH_OFF = 1 + 67108864ULL;
static const size_t COUNTS_OFF   = 1 + 2ULL * 67108864ULL;   // = 134217729

// LDS-only barrier (Round-0): orders ds_write -> barrier -> ds_read without draining vmcnt.
__device__ __forceinline__ void bar_lds_only() {
    asm volatile("s_waitcnt lgkmcnt(0)" ::: "memory");
    __builtin_amdgcn_s_barrier();
}

// ---------------------------------------------------------------- dedicated zero-fill
// 537 MB of zeros (l_aux + combine + dispatch + counts[0..62]) as a pure NT store stream:
// 2048 blocks x 256 threads (8 blocks/CU), grid-stride, no barriers, no LDS — the same
// structure as the rocclr fill that measurably sustains 6.27 TB/s on this box.
// Covers f32x4 [0, 33554448) = floats [0, 134217792). counts[63] is written by k_ranks.
__global__ __launch_bounds__(256) void k_zero(f32x4* __restrict__ zout,
                                              float* __restrict__ colsum) {
    const f32x4 z4 = {0.f, 0.f, 0.f, 0.f};
    long gt = (long)blockIdx.x * 256 + threadIdx.x;          // 0..524287
    #pragma unroll
    for (int i = 0; i < 64; ++i)
        __builtin_nontemporal_store(z4, zout + (long)i * 524288 + gt);
    if (gt < 16) __builtin_nontemporal_store(z4, zout + 33554432 + gt);
    if (blockIdx.x == 0 && threadIdx.x < 64) colsum[threadIdx.x] = 0.f;
}

// ---------------------------------------------------------------- logits GEMM (split-K=4)
// De-fused from the zero-fill: pure GEMM now. grid (128 row-tiles, 4 k-quarters) = 512 blocks.
// Tile 64r x 64e, thread 4r x 4e.
#define RT 64
#define KC 32
__global__ __launch_bounds__(256) void k_gemm(const float* __restrict__ in,
                                              const float* __restrict__ wg,
                                              float* __restrict__ part) {
    __shared__ float in_lds[KC][RT + 4];
    __shared__ float wg_lds[KC][NE + 4];
    int t  = threadIdx.x;
    int r0 = blockIdx.x * RT;
    int kbase = blockIdx.y * (MDIM / 4);
    int te = t & 15, tr = t >> 4;
    int kq  = t & 7;
    int row = t >> 3;
    float acc[4][4] = {};
    for (int c = 0; c < 16; ++c) {
        int k0 = kbase + c * KC;
        float4 v0 = *(const float4*)(in + (size_t)(r0 + row) * MDIM + k0 + kq * 4);
        float4 v1 = *(const float4*)(in + (size_t)(r0 + row + 32) * MDIM + k0 + kq * 4);
        float4 w0 = *(const float4*)(wg + (size_t)row * MDIM + k0 + kq * 4);
        float4 w1 = *(const float4*)(wg + (size_t)(row + 32) * MDIM + k0 + kq * 4);
        in_lds[kq * 4 + 0][row] = v0.x; in_lds[kq * 4 + 1][row] = v0.y;
        in_lds[kq * 4 + 2][row] = v0.z; in_lds[kq * 4 + 3][row] = v0.w;
        in_lds[kq * 4 + 0][row + 32] = v1.x; in_lds[kq * 4 + 1][row + 32] = v1.y;
        in_lds[kq * 4 + 2][row + 32] = v1.z; in_lds[kq * 4 + 3][row + 32] = v1.w;
        wg_lds[kq * 4 + 0][row] = w0.x; wg_lds[kq * 4 + 1][row] = w0.y;
        wg_lds[kq * 4 + 2][row] = w0.z; wg_lds[kq * 4 + 3][row] = w0.w;
        wg_lds[kq * 4 + 0][row + 32] = w1.x; wg_lds[kq * 4 + 1][row + 32] = w1.y;
        wg_lds[kq * 4 + 2][row + 32] = w1.z; wg_lds[kq * 4 + 3][row + 32] = w1.w;
        bar_lds_only();
        #pragma unroll
        for (int kk = 0; kk < KC; ++kk) {
            float4 a4 = *(const float4*)&in_lds[kk][tr * 4];
            float4 b4 = *(const float4*)&wg_lds[kk][te * 4];
            float a[4] = {a4.x, a4.y, a4.z, a4.w};
            float b[4] = {b4.x, b4.y, b4.z, b4.w};
            #pragma unroll
            for (int i = 0; i < 4; ++i)
                #pragma unroll
                for (int j = 0; j < 4; ++j)
                    acc[i][j] += a[i] * b[j];
        }
        bar_lds_only();
    }
    #pragma unroll
    for (int i = 0; i < 4; ++i) {
        size_t base = ((size_t)blockIdx.y * S_TOK + r0 + tr * 4 + i) * NE + te * 4;
        *(float4*)(part + base) = make_float4(acc[i][0], acc[i][1], acc[i][2], acc[i][3]);
    }
}

// ---------------------------------------------------------------- softmax + argmax + seg histogram
// 256 blocks x 32 rows. Also emits segcnt[e][seg] = hits for expert e in this 32-row segment.
__global__ __launch_bounds__(256) void k_softmax(const float* __restrict__ part,
                                                 float* __restrict__ colsum,
                                                 float* __restrict__ gate_sel,
                                                 int* __restrict__ eid,
                                                 int* __restrict__ segcnt) {
    __shared__ float ls[NE];
    __shared__ int hist[NE];
    int t = threadIdx.x;
    int lane = t & 63, w = t >> 6;
    if (t < NE) { ls[t] = 0.f; hist[t] = 0; }
    __syncthreads();
    float lsum = 0.f;
    for (int i = 0; i < 8; ++i) {
        int r = blockIdx.x * 32 + w * 8 + i;
        float v = part[(size_t)r * NE + lane]
                + part[(size_t)(S_TOK + r) * NE + lane]
                + part[(size_t)(2 * S_TOK + r) * NE + lane]
                + part[(size_t)(3 * S_TOK + r) * NE + lane];
        float m = v; int mi = lane;
        for (int off = 32; off > 0; off >>= 1) {
            float om = __shfl_xor(m, off);
            int   oi = __shfl_xor(mi, off);
            if (om > m || (om == m && oi < mi)) { m = om; mi = oi; }
        }
        float ex = expf(v - m);
        float s = ex;
        for (int off = 32; off > 0; off >>= 1) s += __shfl_xor(s, off);
        float gate = ex / s;
        lsum += gate;
        if (lane == mi) { gate_sel[r] = gate; eid[r] = mi; atomicAdd(&hist[mi], 1); }
    }
    atomicAdd(&ls[lane], lsum);
    __syncthreads();
    if (t < NE) {
        atomicAdd(&colsum[t], ls[t]);
        segcnt[t * NSEG + blockIdx.x] = hist[t];   // [e][seg]
    }
}

// ---------------------------------------------------------------- ranks + scatter + counts + l_aux
// Block e: exclusive scan of 256 segment counts (1 barrier), then thread t walks its
// 32-token segment with a running rank. Threads whose base rank >= CAP exit immediately.
__global__ __launch_bounds__(256) void k_ranks_scatter(const int* __restrict__ eid,
                                                       const float* __restrict__ gate_sel,
                                                       const int* __restrict__ segcnt,
                                                       const float* __restrict__ colsum,
                                                       float* __restrict__ out) {
    __shared__ int wsum[4];
    int e = blockIdx.x;
    int t = threadIdx.x;
    int lane = t & 63, w = t >> 6;
    int c = segcnt[e * NSEG + t];
    // inclusive wave scan
    int incl = c;
    #pragma unroll
    for (int off = 1; off < 64; off <<= 1) {
        int v = __shfl_up(incl, off);
        if (lane >= off) incl += v;
    }
    if (lane == 63) wsum[w] = incl;
    __syncthreads();
    int woff = 0;
    #pragma unroll
    for (int j = 0; j < 4; ++j) if (j < w) woff += wsum[j];
    int excl = woff + incl - c;                    // tokens for e before this segment
    if (t == 0) {
        int total = wsum[0] + wsum[1] + wsum[2] + wsum[3];
        out[COUNTS_OFF + e] = (float)total;
        float term = (colsum[e] / 8192.f) * ((float)total / 8192.f) * 64.f;
        atomicAdd(out, term);                      // l_aux (out[0] zeroed by k_zero)
    }
    if (c == 0 || excl >= CAP) return;             // nothing to write from this segment
    int run = excl;
    int base_s = t * 32;
    #pragma unroll 4
    for (int j = 0; j < 32; ++j) {
        if (run >= CAP) break;
        int s = base_s + j;
        if (eid[s] == e) {
            size_t idx = ((size_t)s * NE + e) * CAP + run;
            out[COMBINE_OFF + idx]  = gate_sel[s];
            out[DISPATCH_OFF + idx] = 1.0f;
            ++run;
        }
    }
}

extern "C" void kernel_launch(void* const* d_in, const int* in_sizes, int n_in,
                              void* d_out, int out_size, void* d_ws, size_t ws_size,
                              hipStream_t stream) {
    const float* in = (const float*)d_in[0];
    const float* wg = (const float*)d_in[1];
    float* out = (float*)d_out;

    float* colsum   = (float*)d_ws;              // 64 f
    float* gate_sel = colsum + 64;               // 8192 f
    int*   eid      = (int*)(gate_sel + 8192);   // 8192 i
    int*   segcnt   = eid + 8192;                // 64*256 i
    float* part     = (float*)(segcnt + NE * NSEG);  // 4*8192*64 f

    k_zero<<<2048, 256, 0, stream>>>((f32x4*)out, colsum);
    k_gemm<<<dim3(128, 4), 256, 0, stream>>>(in, wg, part);
    k_softmax<<<256, 256, 0, stream>>>(part, colsum, gate_sel, eid, segcnt);
    k_ranks_scatter<<<64, 256, 0, stream>>>(eid, gate_sel, segcnt, colsum, out);
}

// Round 3
// 610.044 us; speedup vs baseline: 1.0548x; 1.0548x over previous
//
#include <hip/hip_runtime.h>
#include <cstdint>
#include <cstddef>

#define S_TOK 8192
#define MDIM  2048
#define NE    64
#define CAP   128
#define NSEG  256   // 32-token segments

typedef float f32x4 __attribute__((ext_vector_type(4)));

// d_out float layout: [0]=l_aux | [1..+67108864)=combine | [..+67108864)=dispatch | [..+64)=exp_counts
static const size_t COMBINE_OFF  = 1;
static const size_t DISPATCH_OFF = 1 + 67108864ULL;
static const size_t COUNTS_OFF   = 1 + 2ULL * 67108864ULL;   // = 134217729

// LDS-only barrier: orders ds_write -> barrier -> ds_read without draining vmcnt.
__device__ __forceinline__ void bar_lds_only() {
    asm volatile("s_waitcnt lgkmcnt(0)" ::: "memory");
    __builtin_amdgcn_s_barrier();
}

// ---------------------------------------------------------------- logits GEMM (split-K=4)
// grid (128 row-tiles, 4 k-quarters) = 512 blocks. Tile 64r x 64e, thread 4r x 4e.
// Also zero-inits colsum[64] + ws_laux[1] (contiguous) for the downstream atomics.
#define RT 64
#define KC 32
__global__ __launch_bounds__(256) void k_gemm(const float* __restrict__ in,
                                              const float* __restrict__ wg,
                                              float* __restrict__ part,
                                              float* __restrict__ colsum) {
    __shared__ float in_lds[KC][RT + 4];
    __shared__ float wg_lds[KC][NE + 4];
    int t  = threadIdx.x;
    int r0 = blockIdx.x * RT;
    int kbase = blockIdx.y * (MDIM / 4);
    int bid = blockIdx.y * 128 + blockIdx.x;
    if (bid == 0 && t < 65) colsum[t] = 0.f;     // colsum[64] + ws_laux
    int te = t & 15, tr = t >> 4;
    int kq  = t & 7;
    int row = t >> 3;
    float acc[4][4] = {};
    for (int c = 0; c < 16; ++c) {
        int k0 = kbase + c * KC;
        float4 v0 = *(const float4*)(in + (size_t)(r0 + row) * MDIM + k0 + kq * 4);
        float4 v1 = *(const float4*)(in + (size_t)(r0 + row + 32) * MDIM + k0 + kq * 4);
        float4 w0 = *(const float4*)(wg + (size_t)row * MDIM + k0 + kq * 4);
        float4 w1 = *(const float4*)(wg + (size_t)(row + 32) * MDIM + k0 + kq * 4);
        in_lds[kq * 4 + 0][row] = v0.x; in_lds[kq * 4 + 1][row] = v0.y;
        in_lds[kq * 4 + 2][row] = v0.z; in_lds[kq * 4 + 3][row] = v0.w;
        in_lds[kq * 4 + 0][row + 32] = v1.x; in_lds[kq * 4 + 1][row + 32] = v1.y;
        in_lds[kq * 4 + 2][row + 32] = v1.z; in_lds[kq * 4 + 3][row + 32] = v1.w;
        wg_lds[kq * 4 + 0][row] = w0.x; wg_lds[kq * 4 + 1][row] = w0.y;
        wg_lds[kq * 4 + 2][row] = w0.z; wg_lds[kq * 4 + 3][row] = w0.w;
        wg_lds[kq * 4 + 0][row + 32] = w1.x; wg_lds[kq * 4 + 1][row + 32] = w1.y;
        wg_lds[kq * 4 + 2][row + 32] = w1.z; wg_lds[kq * 4 + 3][row + 32] = w1.w;
        bar_lds_only();
        #pragma unroll
        for (int kk = 0; kk < KC; ++kk) {
            float4 a4 = *(const float4*)&in_lds[kk][tr * 4];
            float4 b4 = *(const float4*)&wg_lds[kk][te * 4];
            float a[4] = {a4.x, a4.y, a4.z, a4.w};
            float b[4] = {b4.x, b4.y, b4.z, b4.w};
            #pragma unroll
            for (int i = 0; i < 4; ++i)
                #pragma unroll
                for (int j = 0; j < 4; ++j)
                    acc[i][j] += a[i] * b[j];
        }
        bar_lds_only();
    }
    #pragma unroll
    for (int i = 0; i < 4; ++i) {
        size_t base = ((size_t)blockIdx.y * S_TOK + r0 + tr * 4 + i) * NE + te * 4;
        *(float4*)(part + base) = make_float4(acc[i][0], acc[i][1], acc[i][2], acc[i][3]);
    }
}

// ---------------------------------------------------------------- softmax + argmax + seg histogram
__global__ __launch_bounds__(256) void k_softmax(const float* __restrict__ part,
                                                 float* __restrict__ colsum,
                                                 float* __restrict__ gate_sel,
                                                 int* __restrict__ eid,
                                                 int* __restrict__ segcnt) {
    __shared__ float ls[NE];
    __shared__ int hist[NE];
    int t = threadIdx.x;
    int lane = t & 63, w = t >> 6;
    if (t < NE) { ls[t] = 0.f; hist[t] = 0; }
    __syncthreads();
    float lsum = 0.f;
    for (int i = 0; i < 8; ++i) {
        int r = blockIdx.x * 32 + w * 8 + i;
        float v = part[(size_t)r * NE + lane]
                + part[(size_t)(S_TOK + r) * NE + lane]
                + part[(size_t)(2 * S_TOK + r) * NE + lane]
                + part[(size_t)(3 * S_TOK + r) * NE + lane];
        float m = v; int mi = lane;
        for (int off = 32; off > 0; off >>= 1) {
            float om = __shfl_xor(m, off);
            int   oi = __shfl_xor(mi, off);
            if (om > m || (om == m && oi < mi)) { m = om; mi = oi; }
        }
        float ex = expf(v - m);
        float s = ex;
        for (int off = 32; off > 0; off >>= 1) s += __shfl_xor(s, off);
        float gate = ex / s;
        lsum += gate;
        if (lane == mi) { gate_sel[r] = gate; eid[r] = mi; atomicAdd(&hist[mi], 1); }
    }
    atomicAdd(&ls[lane], lsum);
    __syncthreads();
    if (t < NE) {
        atomicAdd(&colsum[t], ls[t]);
        segcnt[t * NSEG + blockIdx.x] = hist[t];   // [e][seg]
    }
}

// ---------------------------------------------------------------- per-token ranks (no out writes)
// Block e: exclusive scan of 256 segment counts, then thread t walks its 32-token segment.
// Writes rank1[s] (slot within expert, or -1 if over capacity) for every token it owns,
// plus ws_counts[e] and the l_aux term into ws_laux. Every token is visited exactly once
// (by the block of its argmax expert).
__global__ __launch_bounds__(256) void k_ranks(const int* __restrict__ eid,
                                               const int* __restrict__ segcnt,
                                               const float* __restrict__ colsum,
                                               int* __restrict__ rank1,
                                               float* __restrict__ ws_counts,
                                               float* __restrict__ ws_laux) {
    __shared__ int wsum[4];
    int e = blockIdx.x;
    int t = threadIdx.x;
    int lane = t & 63, w = t >> 6;
    int c = segcnt[e * NSEG + t];
    int incl = c;
    #pragma unroll
    for (int off = 1; off < 64; off <<= 1) {
        int v = __shfl_up(incl, off);
        if (lane >= off) incl += v;
    }
    if (lane == 63) wsum[w] = incl;
    __syncthreads();
    int woff = 0;
    #pragma unroll
    for (int j = 0; j < 4; ++j) if (j < w) woff += wsum[j];
    int excl = woff + incl - c;                    // tokens for e before this segment
    if (t == 0) {
        int total = wsum[0] + wsum[1] + wsum[2] + wsum[3];
        ws_counts[e] = (float)total;
        float term = (colsum[e] / 8192.f) * ((float)total / 8192.f) * 64.f;
        atomicAdd(ws_laux, term);
    }
    if (c == 0) return;                            // no tokens of e in this segment
    int run = excl;
    int base_s = t * 32;
    #pragma unroll 4
    for (int j = 0; j < 32; ++j) {
        int s = base_s + j;
        if (eid[s] == e) { rank1[s] = (run < CAP) ? run : -1; ++run; }
    }
}

// ---------------------------------------------------------------- fused zero-fill + scatter
// 2048 blocks; block b owns f32x4 [b*16384, (b+1)*16384) = floats [b*65536, +65536) of out.
// Plain (non-NT) dwordx4 stores, no inner barriers, 8 blocks/CU — same structure as the
// rocclr fill that sustains 6.27 TB/s. After vmcnt(0)+barrier, the <=18 candidate tokens
// whose combine/dispatch float lands in this slice are patched in (reads are L2-resident).
__global__ __launch_bounds__(256) void k_zerowrite(float* __restrict__ out,
                                                   const int* __restrict__ eid,
                                                   const float* __restrict__ gate_sel,
                                                   const int* __restrict__ rank1,
                                                   const float* __restrict__ ws_counts,
                                                   const float* __restrict__ ws_laux) {
    int b = blockIdx.x;
    int t = threadIdx.x;
    f32x4* zo = (f32x4*)out;
    const f32x4 z4 = {0.f, 0.f, 0.f, 0.f};
    long base = (long)b * 16384;
    #pragma unroll
    for (int i = 0; i < 64; ++i)
        zo[base + (long)i * 256 + t] = z4;
    if (b == 2047 && t < 16) zo[33554432 + t] = z4;   // tail: last dispatch float + counts region
    asm volatile("s_waitcnt vmcnt(0)" ::: "memory");
    __syncthreads();

    long B0 = (long)b * 65536;                     // float range [B0, B1) owned by this block
    long B1 = B0 + 65536;
    // --- combine candidates: floats g = 1 + s*8192 + e*128 + r
    if (t < 9) {
        long s_lo = (B0 > 0) ? ((B0 - 1) >> 13) : 0;
        long s_hi = (B1 - 2) >> 13;
        long s = s_lo + t;
        if (s <= s_hi && s < S_TOK) {
            int e = eid[s], r = rank1[s];
            if (r >= 0) {
                long g = 1 + (s << 13) + ((long)e << 7) + r;
                if (g >= B0 && g < B1) out[g] = gate_sel[s];
            }
        }
    }
    // --- dispatch candidates: floats d = 67108864 + (1 + s*8192 + e*128 + r)
    if (t >= 16 && t < 25) {
        long C0 = B0 - 67108864;
        long C1 = C0 + 65536;
        if (C1 >= 2) {
            long s_lo = (C0 > 0) ? ((C0 - 1) >> 13) : 0;
            long s_hi = (C1 - 2) >> 13;
            long s = s_lo + (t - 16);
            if (s <= s_hi && s < S_TOK) {
                int e = eid[s], r = rank1[s];
                if (r >= 0) {
                    long d = 67108864 + 1 + (s << 13) + ((long)e << 7) + r;
                    if (d >= B0 && d < B1) out[d] = 1.0f;
                }
            }
        }
    }
    // --- singletons
    if (b == 0 && t == 0) out[0] = *ws_laux;                         // l_aux (owned slice)
    if (b == 2047) {
        if (t < 64) out[COUNTS_OFF + t] = ws_counts[t];              // exp_counts (tail region)
        if (t == 64) {                                               // dispatch float 134217728
            int e = eid[S_TOK - 1], r = rank1[S_TOK - 1];            // (token 8191, e=63, r=127)
            if (e == NE - 1 && r == CAP - 1) out[134217728] = 1.0f;
        }
    }
}

extern "C" void kernel_launch(void* const* d_in, const int* in_sizes, int n_in,
                              void* d_out, int out_size, void* d_ws, size_t ws_size,
                              hipStream_t stream) {
    const float* in = (const float*)d_in[0];
    const float* wg = (const float*)d_in[1];
    float* out = (float*)d_out;

    float* colsum    = (float*)d_ws;                 // 64 f  (+1 ws_laux, contiguous)
    float* ws_laux   = colsum + 64;                  // 1 f
    float* ws_counts = ws_laux + 1;                  // 64 f
    float* gate_sel  = ws_counts + 64;               // 8192 f
    int*   eid       = (int*)(gate_sel + 8192);      // 8192 i
    int*   rank1     = eid + 8192;                   // 8192 i
    int*   segcnt    = rank1 + 8192;                 // 64*256 i
    float* part      = (float*)(segcnt + NE * NSEG); // 4*8192*64 f

    k_gemm<<<dim3(128, 4), 256, 0, stream>>>(in, wg, part, colsum);
    k_softmax<<<256, 256, 0, stream>>>(part, colsum, gate_sel, eid, segcnt);
    k_ranks<<<64, 256, 0, stream>>>(eid, segcnt, colsum, rank1, ws_counts, ws_laux);
    k_zerowrite<<<2048, 256, 0, stream>>>(out, eid, gate_sel, rank1, ws_counts, ws_laux);
}

// Round 4
// 537.961 us; speedup vs baseline: 1.1962x; 1.1340x over previous
//
#include <hip/hip_runtime.h>
#include <cstdint>
#include <cstddef>

#define S_TOK 8192
#define MDIM  2048
#define NE    64
#define CAP   128
#define NSEG  256   // 32-token segments

typedef float f32x4 __attribute__((ext_vector_type(4)));

// d_out float layout: [0]=l_aux | [1..+67108864)=combine | [..+67108864)=dispatch | [..+64)=exp_counts
static const size_t COMBINE_OFF  = 1;
static const size_t DISPATCH_OFF = 1 + 67108864ULL;
static const size_t COUNTS_OFF   = 1 + 2ULL * 67108864ULL;   // = 134217729

// LDS-only barrier: orders ds_write -> barrier -> ds_read without draining vmcnt.
__device__ __forceinline__ void bar_lds_only() {
    asm volatile("s_waitcnt lgkmcnt(0)" ::: "memory");
    __builtin_amdgcn_s_barrier();
}

// ---------------------------------------------------------------- logits GEMM (split-K=4)
// grid (128 row-tiles, 4 k-quarters) = 512 blocks. Tile 64r x 64e, thread 4r x 4e.
// Pure GEMM; the output zero-fill is now a hipMemsetAsync (rocclr fill path, 6.27 TB/s
// measured on this very allocation). Also zero-inits colsum[64] for softmax atomics.
#define RT 64
#define KC 32
__global__ __launch_bounds__(256) void k_gemm(const float* __restrict__ in,
                                              const float* __restrict__ wg,
                                              float* __restrict__ part,
                                              float* __restrict__ colsum) {
    __shared__ float in_lds[KC][RT + 4];
    __shared__ float wg_lds[KC][NE + 4];
    int t  = threadIdx.x;
    int r0 = blockIdx.x * RT;
    int kbase = blockIdx.y * (MDIM / 4);
    int bid = blockIdx.y * 128 + blockIdx.x;
    if (bid == 0 && t < 64) colsum[t] = 0.f;
    int te = t & 15, tr = t >> 4;
    int kq  = t & 7;
    int row = t >> 3;
    float acc[4][4] = {};
    for (int c = 0; c < 16; ++c) {
        int k0 = kbase + c * KC;
        float4 v0 = *(const float4*)(in + (size_t)(r0 + row) * MDIM + k0 + kq * 4);
        float4 v1 = *(const float4*)(in + (size_t)(r0 + row + 32) * MDIM + k0 + kq * 4);
        float4 w0 = *(const float4*)(wg + (size_t)row * MDIM + k0 + kq * 4);
        float4 w1 = *(const float4*)(wg + (size_t)(row + 32) * MDIM + k0 + kq * 4);
        in_lds[kq * 4 + 0][row] = v0.x; in_lds[kq * 4 + 1][row] = v0.y;
        in_lds[kq * 4 + 2][row] = v0.z; in_lds[kq * 4 + 3][row] = v0.w;
        in_lds[kq * 4 + 0][row + 32] = v1.x; in_lds[kq * 4 + 1][row + 32] = v1.y;
        in_lds[kq * 4 + 2][row + 32] = v1.z; in_lds[kq * 4 + 3][row + 32] = v1.w;
        wg_lds[kq * 4 + 0][row] = w0.x; wg_lds[kq * 4 + 1][row] = w0.y;
        wg_lds[kq * 4 + 2][row] = w0.z; wg_lds[kq * 4 + 3][row] = w0.w;
        wg_lds[kq * 4 + 0][row + 32] = w1.x; wg_lds[kq * 4 + 1][row + 32] = w1.y;
        wg_lds[kq * 4 + 2][row + 32] = w1.z; wg_lds[kq * 4 + 3][row + 32] = w1.w;
        bar_lds_only();
        #pragma unroll
        for (int kk = 0; kk < KC; ++kk) {
            float4 a4 = *(const float4*)&in_lds[kk][tr * 4];
            float4 b4 = *(const float4*)&wg_lds[kk][te * 4];
            float a[4] = {a4.x, a4.y, a4.z, a4.w};
            float b[4] = {b4.x, b4.y, b4.z, b4.w};
            #pragma unroll
            for (int i = 0; i < 4; ++i)
                #pragma unroll
                for (int j = 0; j < 4; ++j)
                    acc[i][j] += a[i] * b[j];
        }
        bar_lds_only();
    }
    #pragma unroll
    for (int i = 0; i < 4; ++i) {
        size_t base = ((size_t)blockIdx.y * S_TOK + r0 + tr * 4 + i) * NE + te * 4;
        *(float4*)(part + base) = make_float4(acc[i][0], acc[i][1], acc[i][2], acc[i][3]);
    }
}

// ---------------------------------------------------------------- softmax + argmax + seg histogram
// 256 blocks x 1024 threads (16 waves/CU, was 4): each wave handles 2 rows instead of 8.
// Theory: this kernel was latency-bound at 12.5% occupancy (serial shuffle chains + far-apart
// part reads, 1 block/CU). Same segment structure (NSEG=256), k_ranks_scatter unchanged.
__global__ __launch_bounds__(1024) void k_softmax(const float* __restrict__ part,
                                                  float* __restrict__ colsum,
                                                  float* __restrict__ gate_sel,
                                                  int* __restrict__ eid,
                                                  int* __restrict__ segcnt) {
    __shared__ float ls[NE];
    __shared__ int hist[NE];
    int t = threadIdx.x;
    int lane = t & 63, w = t >> 6;          // w in 0..15
    if (t < NE) { ls[t] = 0.f; hist[t] = 0; }
    __syncthreads();
    float lsum = 0.f;
    #pragma unroll
    for (int i = 0; i < 2; ++i) {
        int r = blockIdx.x * 32 + w * 2 + i;
        float v = part[(size_t)r * NE + lane]
                + part[(size_t)(S_TOK + r) * NE + lane]
                + part[(size_t)(2 * S_TOK + r) * NE + lane]
                + part[(size_t)(3 * S_TOK + r) * NE + lane];
        float m = v; int mi = lane;
        for (int off = 32; off > 0; off >>= 1) {
            float om = __shfl_xor(m, off);
            int   oi = __shfl_xor(mi, off);
            if (om > m || (om == m && oi < mi)) { m = om; mi = oi; }
        }
        float ex = expf(v - m);
        float s = ex;
        for (int off = 32; off > 0; off >>= 1) s += __shfl_xor(s, off);
        float gate = ex / s;
        lsum += gate;
        if (lane == mi) { gate_sel[r] = gate; eid[r] = mi; atomicAdd(&hist[mi], 1); }
    }
    atomicAdd(&ls[lane], lsum);
    __syncthreads();
    if (t < NE) {
        atomicAdd(&colsum[t], ls[t]);
        segcnt[t * NSEG + blockIdx.x] = hist[t];   // [e][seg]
    }
}

// ---------------------------------------------------------------- ranks + scatter + counts + l_aux
// Block e: exclusive scan of 256 segment counts, then thread t walks its 32-token segment
// with a running rank, scattering into the memset-zeroed output.
__global__ __launch_bounds__(256) void k_ranks_scatter(const int* __restrict__ eid,
                                                       const float* __restrict__ gate_sel,
                                                       const int* __restrict__ segcnt,
                                                       const float* __restrict__ colsum,
                                                       float* __restrict__ out) {
    __shared__ int wsum[4];
    int e = blockIdx.x;
    int t = threadIdx.x;
    int lane = t & 63, w = t >> 6;
    int c = segcnt[e * NSEG + t];
    // inclusive wave scan
    int incl = c;
    #pragma unroll
    for (int off = 1; off < 64; off <<= 1) {
        int v = __shfl_up(incl, off);
        if (lane >= off) incl += v;
    }
    if (lane == 63) wsum[w] = incl;
    __syncthreads();
    int woff = 0;
    #pragma unroll
    for (int j = 0; j < 4; ++j) if (j < w) woff += wsum[j];
    int excl = woff + incl - c;                    // tokens for e before this segment
    if (t == 0) {
        int total = wsum[0] + wsum[1] + wsum[2] + wsum[3];
        out[COUNTS_OFF + e] = (float)total;
        float term = (colsum[e] / 8192.f) * ((float)total / 8192.f) * 64.f;
        atomicAdd(out, term);                      // l_aux (out[0] zeroed by memset)
    }
    if (c == 0 || excl >= CAP) return;             // nothing to write from this segment
    int run = excl;
    int base_s = t * 32;
    #pragma unroll 4
    for (int j = 0; j < 32; ++j) {
        if (run >= CAP) break;
        int s = base_s + j;
        if (eid[s] == e) {
            size_t idx = ((size_t)s * NE + e) * CAP + run;
            out[COMBINE_OFF + idx]  = gate_sel[s];
            out[DISPATCH_OFF + idx] = 1.0f;
            ++run;
        }
    }
}

extern "C" void kernel_launch(void* const* d_in, const int* in_sizes, int n_in,
                              void* d_out, int out_size, void* d_ws, size_t ws_size,
                              hipStream_t stream) {
    const float* in = (const float*)d_in[0];
    const float* wg = (const float*)d_in[1];
    float* out = (float*)d_out;

    float* colsum   = (float*)d_ws;              // 64 f
    float* gate_sel = colsum + 64;               // 8192 f
    int*   eid      = (int*)(gate_sel + 8192);   // 8192 i
    int*   segcnt   = eid + 8192;                // 64*256 i
    float* part     = (float*)(segcnt + NE * NSEG);  // 4*8192*64 f

    // Zero the whole output via the rocclr fill path (measured 6.27 TB/s on this buffer).
    hipMemsetAsync(d_out, 0, (size_t)out_size, stream);
    k_gemm<<<dim3(128, 4), 256, 0, stream>>>(in, wg, part, colsum);
    k_softmax<<<256, 1024, 0, stream>>>(part, colsum, gate_sel, eid, segcnt);
    k_ranks_scatter<<<64, 256, 0, stream>>>(eid, gate_sel, segcnt, colsum, out);
}